// Round 2
// 645.928 us; speedup vs baseline: 1.0349x; 1.0349x over previous
//
#include <hip/hip_runtime.h>
#include <stdint.h>

// IrrepsLinear: out[n,m,:] = x[n,m,:] @ W[seg(m)]
// N=50000 nodes, M=16 spherical components, C_in=C_out=128, 4 weight matrices.
// bf16 MFMA, weights register-resident per wave, HBM streaming of x/out.
// This revision: per-wave LDS staging with XOR swizzle so every global
// load/store is 1KB/instruction in 512B contiguous segments (was: 64x16B
// scattered read segments, 64B write segments). Floor ~128us @6.4TB/s.

typedef __attribute__((ext_vector_type(8))) short short8;   // 8 bf16 in 4 VGPRs
typedef __attribute__((ext_vector_type(4))) short sh4;      // 4 bf16 in 2 VGPRs
typedef __attribute__((ext_vector_type(4))) float floatx4;

static __device__ __forceinline__ unsigned short f2bf(float f) {
    // round-to-nearest-even fp32 -> bf16
    uint32_t u = __builtin_bit_cast(uint32_t, f);
    uint32_t r = (u + 0x7FFFu + ((u >> 16) & 1u)) >> 16;
    return (unsigned short)r;
}

// Pack weights (4 x 128 x 128 fp32, row-major [s][c][d]) into bf16 in exact
// MFMA B-fragment order for mfma_f32_16x16x32_bf16:
//   B[k][ncol]: lane holds col = lane&15, k = (lane>>4)*8 + j, j=0..7
// Layout: wp[(((s*8 + dt)*4 + kt)*64 + lane)*8 + j]
//   c = kt*32 + (lane>>4)*8 + j ; d = dt*16 + (lane&15)
__global__ void pack_weights_kernel(const float* __restrict__ w,
                                    unsigned short* __restrict__ wp) {
    int tid = blockIdx.x * 256 + threadIdx.x;      // 0..65535
    int j    = tid & 7;
    int lane = (tid >> 3) & 63;
    int kt   = (tid >> 9) & 3;
    int dt   = (tid >> 11) & 7;
    int s    = (tid >> 14) & 3;
    int c = kt * 32 + (lane >> 4) * 8 + j;
    int d = dt * 16 + (lane & 15);
    wp[tid] = f2bf(w[((size_t)s * 128 + c) * 128 + d]);
}

// Main kernel: 512 blocks x 256 threads = 2048 waves.
// wave -> (m = waveId>>7, stripe of 16-node tiles, stride 128 waves/m).
// 50000 nodes = 3125 tiles of 16, exactly.
//
// Per-wave private LDS (no cross-wave sharing -> no barriers):
//   xa: [16 rows][256B] bf16 x-tile, row r swizzled byte ^= ((r&7)<<4)
//   ob: [16 rows][512B] fp32 out-tile, same swizzle
// Swizzle keeps all DS ops <=2-way bank aliased (free) and makes the
// 16-lane same-column fragment read uniform across 16B bank groups.
__global__ __launch_bounds__(256, 2) void irreps_main_kernel(
    const float* __restrict__ x, const unsigned short* __restrict__ wp,
    const int* __restrict__ seg_ids, float* __restrict__ out)
{
    __shared__ char lds_all[4][12 * 1024];   // 48KB/block -> 2 blocks/CU = 96KB

    const int lane = threadIdx.x & 63;
    const int wib  = threadIdx.x >> 6;
    char* const xa = lds_all[wib];           // 4KB bf16 tile
    char* const ob = lds_all[wib] + 4096;    // 8KB fp32 tile

    const int waveId = blockIdx.x * 4 + wib;                 // 0..2047
    const int m      = waveId >> 7;                          // 0..15
    const int w_in_m = waveId & 127;
    const int seg    = seg_ids[m];                           // wave-uniform
    const int q      = lane >> 4;                            // 0..3
    const int ln15   = lane & 15;
    const int nsub   = lane >> 5;                            // 0..1
    const int c16    = lane & 31;                            // 16B unit in 512B row

    // B fragments for this wave's weight matrix: 8 d-tiles x 4 k-tiles.
    // 32 x 16B = 128 VGPRs, register-resident for the whole kernel.
    short8 B[8][4];
    {
        const unsigned short* wb = wp + ((size_t)seg << 14);  // seg*8*4*64*8
        #pragma unroll
        for (int dt = 0; dt < 8; ++dt)
            #pragma unroll
            for (int kt = 0; kt < 4; ++kt)
                B[dt][kt] = *(const short8*)(wb + (((dt * 4 + kt) * 64 + lane) << 3));
    }

    // Precomputed swizzled A-fragment read offsets:
    // row = ln15, unswizzled byte = (kt*32 + q*8)*2 = kt*64 + q*16
    int xa_rd[4];
    #pragma unroll
    for (int kt = 0; kt < 4; ++kt)
        xa_rd[kt] = ln15 * 256 + ((kt * 64 + q * 16) ^ ((ln15 & 7) << 4));

    for (int t = w_in_m; t < 3125; t += 128) {
        const int node0 = t << 4;

        // ---- Phase A: coalesced global read (1KB/instr, 2x512B segments),
        //      fp32->bf16 convert, swizzled LDS write (b64, 2-way max).
        #pragma unroll
        for (int r = 0; r < 8; ++r) {
            const int node = 2 * r + nsub;
            const float* gp = x + (((size_t)(node0 + node) * 16 + m) << 7) + c16 * 4;
            floatx4 v = *(const floatx4*)gp;
            sh4 h;
            h[0] = (short)f2bf(v[0]);
            h[1] = (short)f2bf(v[1]);
            h[2] = (short)f2bf(v[2]);
            h[3] = (short)f2bf(v[3]);
            *(sh4*)(xa + node * 256 + ((c16 * 8) ^ ((node & 7) << 4))) = h;
        }

        // ---- Phase B: A-fragment ds_read_b128 (uniform bank groups) + MFMA
        short8 A[4];
        #pragma unroll
        for (int kt = 0; kt < 4; ++kt)
            A[kt] = *(const short8*)(xa + xa_rd[kt]);

        floatx4 acc[8];
        #pragma unroll
        for (int dt = 0; dt < 8; ++dt) acc[dt] = (floatx4){0.f, 0.f, 0.f, 0.f};

        #pragma unroll
        for (int kt = 0; kt < 4; ++kt)
            #pragma unroll
            for (int dt = 0; dt < 8; ++dt)
                acc[dt] = __builtin_amdgcn_mfma_f32_16x16x32_bf16(
                    A[kt], B[dt][kt], acc[dt], 0, 0, 0);

        // ---- Phase C: accumulator -> swizzled fp32 LDS tile.
        // C/D layout (verified, m89/m91): col = lane&15, row = q*4 + reg.
        #pragma unroll
        for (int i = 0; i < 4; ++i) {
            const int row = q * 4 + i;
            char* rp = ob + row * 512;
            const int sw = (row & 7) << 4;
            #pragma unroll
            for (int dt = 0; dt < 8; ++dt)
                *(float*)(rp + ((dt * 64 + ln15 * 4) ^ sw)) = acc[dt][i];
        }

        // ---- Phase D: LDS readback (b128) + coalesced global store
        //      (1KB/instr, 2x512B segments).
        #pragma unroll
        for (int p = 0; p < 8; ++p) {
            const int node = 2 * p + nsub;
            floatx4 v = *(const floatx4*)(ob + node * 512 +
                                          ((c16 * 16) ^ ((node & 7) << 4)));
            float* gp = out + (((size_t)(node0 + node) * 16 + m) << 7) + c16 * 4;
            *(floatx4*)gp = v;
        }
    }
}

extern "C" void kernel_launch(void* const* d_in, const int* in_sizes, int n_in,
                              void* d_out, int out_size, void* d_ws, size_t ws_size,
                              hipStream_t stream) {
    const float* x   = (const float*)d_in[0];
    const float* w   = (const float*)d_in[1];
    const int*   seg = (const int*)d_in[2];
    float* out = (float*)d_out;
    unsigned short* wp = (unsigned short*)d_ws;  // 65536 ushort = 128 KB

    hipLaunchKernelGGL(pack_weights_kernel, dim3(256), dim3(256), 0, stream, w, wp);
    hipLaunchKernelGGL(irreps_main_kernel, dim3(512), dim3(256), 0, stream,
                       x, wp, seg, out);
}